// Round 4
// baseline (94232.483 us; speedup 1.0000x reference)
//
#include <hip/hip_runtime.h>
#include <stdint.h>

#define BS 8192
#define ECN 1024
#define CA1N 1024
#define CA3N 1024
#define T_STEPS 100
#define CUE_T 10

// ---------------- threefry2x32 (JAX-exact core) ----------------
__host__ __device__ inline uint32_t rotl32_(uint32_t x, uint32_t r) {
    return (x << r) | (x >> (32u - r));
}

__host__ __device__ inline void tf2x32(uint32_t k0, uint32_t k1,
                                       uint32_t x0, uint32_t x1,
                                       uint32_t &o0, uint32_t &o1) {
    uint32_t ks2 = k0 ^ k1 ^ 0x1BD11BDAu;
    x0 += k0; x1 += k1;
#define TF_R4(a,b,c,d) \
    x0 += x1; x1 = rotl32_(x1,(a)); x1 ^= x0; \
    x0 += x1; x1 = rotl32_(x1,(b)); x1 ^= x0; \
    x0 += x1; x1 = rotl32_(x1,(c)); x1 ^= x0; \
    x0 += x1; x1 = rotl32_(x1,(d)); x1 ^= x0;
    TF_R4(13,15,26,6)  x0 += k1;  x1 += ks2 + 1u;
    TF_R4(17,29,16,24) x0 += ks2; x1 += k0 + 2u;
    TF_R4(13,15,26,6)  x0 += k0;  x1 += k1 + 3u;
    TF_R4(17,29,16,24) x0 += k1;  x1 += ks2 + 4u;
    TF_R4(13,15,26,6)  x0 += ks2; x1 += k0 + 5u;
#undef TF_R4
    o0 = x0; o1 = x1;
}

// 0.2*bernoulli, JAX partitionable-threefry 32-bit path:
// per element flat index i: counter = (0, i); bits = o0 ^ o1;
// u = f32_bitcast((bits>>9)|0x3f800000) - 1; spike = u < f32(0.004).
__device__ inline double noise_add(uint32_t k0, uint32_t k1, uint32_t idx) {
    uint32_t o0, o1;
    tf2x32(k0, k1, 0u, idx, o0, o1);
    uint32_t bits = o0 ^ o1;
    float u = __uint_as_float((bits >> 9) | 0x3f800000u) - 1.0f;
    return (u < 0.004f) ? 0.2 : 0.0;
}

__device__ inline double sigmoid64_(double x) {
    return 1.0 / (1.0 + exp(-x));
}

// ---------------- init: ec3 = 0, ec5 = ec5_init (f64) ----------------
__global__ void init_kernel(const float* __restrict__ ec5_init,
                            double* __restrict__ ec3, double* __restrict__ ec5, int n) {
    int i = blockIdx.x * blockDim.x + threadIdx.x;
    if (i < n) { ec3[i] = 0.0; ec5[i] = (double)ec5_init[i]; }
}

// ---------------- drive[t][c] = sum_j exp(-(cen_j - t)^2/50) * W[j][c] (f64) ----------------
__global__ void drive_kernel(const float* __restrict__ wca3ca1, double* __restrict__ drive) {
    int t = blockIdx.x;
    int c0 = threadIdx.x;                 // 256 threads, 4 columns each
    const float stepf = 100.0f / 1023.0f; // f32 centers, matching jnp.linspace f32
    double x = (double)t;
    double acc[4] = {0.0, 0.0, 0.0, 0.0};
    for (int j = 0; j < CA3N; ++j) {
        float cj = stepf * (float)j;
        double d = (double)cj - x;
        double g = exp(-(d * d) / 50.0);
        #pragma unroll
        for (int i = 0; i < 4; ++i)
            acc[i] += g * (double)wca3ca1[(size_t)j * CA1N + c0 + i * 256];
    }
    #pragma unroll
    for (int i = 0; i < 4; ++i)
        drive[(size_t)t * CA1N + c0 + i * 256] = acc[i];
}

// ---------------- tiled fp64 GEMM bodies ----------------
#define TM 64
#define TKK 16
#define LDSP 66   // padded row stride (doubles); 528B rows, 16B-aligned

// ca1 = relu(drive_t * (1 + sigmoid(ec3 @ W1)) - ca1bias)   [ca1 stored f32]
__global__ __launch_bounds__(256) void gemm1_kernel(
    const double* __restrict__ A,     // ec3: BS x ECN (f64)
    const float* __restrict__ W,      // wec3ca1: ECN x CA1N (f32)
    const double* __restrict__ drv,   // drive + t*CA1N (f64)
    const float* __restrict__ bias,   // ca1bias
    float* __restrict__ C)            // ca1 (f32)
{
    __shared__ __align__(16) double As[TKK][LDSP];  // As[k][m]
    __shared__ __align__(16) double Ws[TKK][LDSP];  // Ws[k][n]
    const int tid = threadIdx.x;
    const int tx = tid & 15, ty = tid >> 4;
    const int row0 = blockIdx.x * TM, col0 = blockIdx.y * TM;
    const int ar = tid >> 2, ak = (tid & 3) << 2;   // A loader: row, k-offset
    const int wk = tid >> 4, wn = (tid & 15) << 2;  // W loader: k-row, n-offset
    double acc[4][4] = {};
    for (int k0 = 0; k0 < ECN; k0 += TKK) {
        const double2* Ap = reinterpret_cast<const double2*>(&A[(size_t)(row0 + ar) * ECN + k0 + ak]);
        double2 a01 = Ap[0], a23 = Ap[1];
        float4 w4 = *reinterpret_cast<const float4*>(&W[(size_t)(k0 + wk) * CA1N + col0 + wn]);
        __syncthreads();
        As[ak + 0][ar] = a01.x; As[ak + 1][ar] = a01.y;
        As[ak + 2][ar] = a23.x; As[ak + 3][ar] = a23.y;
        Ws[wk][wn + 0] = (double)w4.x; Ws[wk][wn + 1] = (double)w4.y;
        Ws[wk][wn + 2] = (double)w4.z; Ws[wk][wn + 3] = (double)w4.w;
        __syncthreads();
        #pragma unroll
        for (int k = 0; k < TKK; ++k) {
            double2 av01 = *reinterpret_cast<const double2*>(&As[k][ty << 2]);
            double2 av23 = *reinterpret_cast<const double2*>(&As[k][(ty << 2) + 2]);
            double2 wv01 = *reinterpret_cast<const double2*>(&Ws[k][tx << 2]);
            double2 wv23 = *reinterpret_cast<const double2*>(&Ws[k][(tx << 2) + 2]);
            double a[4] = {av01.x, av01.y, av23.x, av23.y};
            double b[4] = {wv01.x, wv01.y, wv23.x, wv23.y};
            #pragma unroll
            for (int i = 0; i < 4; ++i)
                #pragma unroll
                for (int j = 0; j < 4; ++j)
                    acc[i][j] = fma(a[i], b[j], acc[i][j]);
        }
    }
    #pragma unroll
    for (int i = 0; i < 4; ++i) {
        int r = row0 + (ty << 2) + i;
        #pragma unroll
        for (int j = 0; j < 4; ++j) {
            int c = col0 + (tx << 2) + j;
            double s = sigmoid64_(acc[i][j]);
            double v = drv[c] * (1.0 + s) - (double)bias[c];
            C[(size_t)r * CA1N + c] = (float)(v > 0.0 ? v : 0.0);
        }
    }
}

// u = ec5 + ca1@W2 + ec5bias; ec5' = 0.5+0.5*sig(4(u-0.5)); ec3' = ec5'*ec3 + m*cue + 0.2*bern
__global__ __launch_bounds__(256) void gemm2_kernel(
    const float* __restrict__ A,      // ca1: BS x CA1N (f32)
    const float* __restrict__ W,      // wca1ec5: CA1N x ECN (f32)
    const float* __restrict__ cue,    // BS x ECN (f32)
    const float* __restrict__ bias,   // ec5bias
    double* __restrict__ ec3,
    double* __restrict__ ec5,
    uint32_t k0_, uint32_t k1_, int inject)
{
    __shared__ __align__(16) double As[TKK][LDSP];
    __shared__ __align__(16) double Ws[TKK][LDSP];
    const int tid = threadIdx.x;
    const int tx = tid & 15, ty = tid >> 4;
    const int row0 = blockIdx.x * TM, col0 = blockIdx.y * TM;
    const int ar = tid >> 2, ak = (tid & 3) << 2;
    const int wk = tid >> 4, wn = (tid & 15) << 2;
    double acc[4][4] = {};
    for (int k0 = 0; k0 < CA1N; k0 += TKK) {
        float4 a4 = *reinterpret_cast<const float4*>(&A[(size_t)(row0 + ar) * CA1N + k0 + ak]);
        float4 w4 = *reinterpret_cast<const float4*>(&W[(size_t)(k0 + wk) * ECN + col0 + wn]);
        __syncthreads();
        As[ak + 0][ar] = (double)a4.x; As[ak + 1][ar] = (double)a4.y;
        As[ak + 2][ar] = (double)a4.z; As[ak + 3][ar] = (double)a4.w;
        Ws[wk][wn + 0] = (double)w4.x; Ws[wk][wn + 1] = (double)w4.y;
        Ws[wk][wn + 2] = (double)w4.z; Ws[wk][wn + 3] = (double)w4.w;
        __syncthreads();
        #pragma unroll
        for (int k = 0; k < TKK; ++k) {
            double2 av01 = *reinterpret_cast<const double2*>(&As[k][ty << 2]);
            double2 av23 = *reinterpret_cast<const double2*>(&As[k][(ty << 2) + 2]);
            double2 wv01 = *reinterpret_cast<const double2*>(&Ws[k][tx << 2]);
            double2 wv23 = *reinterpret_cast<const double2*>(&Ws[k][(tx << 2) + 2]);
            double a[4] = {av01.x, av01.y, av23.x, av23.y};
            double b[4] = {wv01.x, wv01.y, wv23.x, wv23.y};
            #pragma unroll
            for (int i = 0; i < 4; ++i)
                #pragma unroll
                for (int j = 0; j < 4; ++j)
                    acc[i][j] = fma(a[i], b[j], acc[i][j]);
        }
    }
    #pragma unroll
    for (int i = 0; i < 4; ++i) {
        int r = row0 + (ty << 2) + i;
        #pragma unroll
        for (int j = 0; j < 4; ++j) {
            int c = col0 + (tx << 2) + j;
            size_t off = (size_t)r * ECN + c;
            double u = ec5[off] + acc[i][j] + (double)bias[c];
            double e5n = 0.5 + 0.5 * sigmoid64_(4.0 * (u - 0.5));
            double e3n = e5n * ec3[off];
            if (inject) e3n += (double)cue[off];       // ec3 = ec5*ec3 + m*cue
            e3n += noise_add(k0_, k1_, (uint32_t)off); // + 0.2*bern (partitionable)
            ec5[off] = e5n;
            ec3[off] = e3n;
        }
    }
}

// out[b][:2] = ca1[b] @ wca1act + actbias  (one wave per row, f64 accumulate)
__global__ __launch_bounds__(256) void final_kernel(
    const float* __restrict__ ca1,
    const float* __restrict__ wact,   // CA1N x 2
    const float* __restrict__ actbias,
    float* __restrict__ out)
{
    int wave = threadIdx.x >> 6, lane = threadIdx.x & 63;
    int b = blockIdx.x * 4 + wave;
    double a0 = 0.0, a1 = 0.0;
    for (int c = lane; c < CA1N; c += 64) {
        double v = (double)ca1[(size_t)b * CA1N + c];
        a0 += v * (double)wact[c * 2 + 0];
        a1 += v * (double)wact[c * 2 + 1];
    }
    #pragma unroll
    for (int off = 32; off > 0; off >>= 1) {
        a0 += __shfl_down(a0, off);
        a1 += __shfl_down(a1, off);
    }
    if (lane == 0) {
        out[(size_t)b * 2 + 0] = (float)(a0 + (double)actbias[0]);
        out[(size_t)b * 2 + 1] = (float)(a1 + (double)actbias[1]);
    }
}

// ---------------- host ----------------
extern "C" void kernel_launch(void* const* d_in, const int* in_sizes, int n_in,
                              void* d_out, int out_size, void* d_ws, size_t ws_size,
                              hipStream_t stream) {
    const float* cue      = (const float*)d_in[0];
    const float* ec5_init = (const float*)d_in[1];
    const float* wca3ca1  = (const float*)d_in[2];
    const float* wec3ca1  = (const float*)d_in[3];
    const float* wca1ec5  = (const float*)d_in[4];
    const float* wca1act  = (const float*)d_in[5];
    const float* ca1bias  = (const float*)d_in[6];
    const float* ec5bias  = (const float*)d_in[7];
    const float* actbias  = (const float*)d_in[8];
    float* out = (float*)d_out;

    double* ec3   = (double*)d_ws;                         // BS*ECN f64   (64 MB)
    double* ec5   = ec3 + (size_t)BS * ECN;                // BS*ECN f64   (64 MB)
    double* drive = ec5 + (size_t)BS * ECN;                // T*CA1N f64   (0.8 MB)
    float*  ca1   = (float*)(drive + (size_t)T_STEPS * CA1N); // BS*CA1N f32 (32 MB)

    const int n = BS * ECN;
    hipLaunchKernelGGL(init_kernel, dim3((n + 255) / 256), dim3(256), 0, stream,
                       ec5_init, ec3, ec5, n);
    hipLaunchKernelGGL(drive_kernel, dim3(T_STEPS), dim3(256), 0, stream,
                       wca3ca1, drive);

    dim3 blk(256);
    dim3 g1(BS / TM, CA1N / TM);
    dim3 g2(BS / TM, ECN / TM);
    for (int t = 0; t < T_STEPS; ++t) {
        uint32_t k0, k1;
        tf2x32(0u, 42u, 0u, (uint32_t)t, k0, k1);   // fold_in(key(42), t)
        hipLaunchKernelGGL(gemm1_kernel, g1, blk, 0, stream,
                           ec3, wec3ca1, drive + (size_t)t * CA1N, ca1bias, ca1);
        hipLaunchKernelGGL(gemm2_kernel, g2, blk, 0, stream,
                           ca1, wca1ec5, cue, ec5bias, ec3, ec5, k0, k1,
                           (t == CUE_T) ? 1 : 0);
    }
    hipLaunchKernelGGL(final_kernel, dim3(BS / 4), blk, 0, stream,
                       ca1, wca1act, actbias, out);
}

// Round 5
// 9021.559 us; speedup vs baseline: 10.4453x; 10.4453x over previous
//
#include <hip/hip_runtime.h>
#include <stdint.h>

#define BS 8192
#define ECN 1024
#define CA1N 1024
#define T_STEPS 100
#define CUE_T 10
#define BK 32

typedef __attribute__((ext_vector_type(8))) short bf16x8;
typedef __attribute__((ext_vector_type(4))) float f32x4;

// ---------------- bf16 helpers (RNE, XLA-compatible) ----------------
__device__ inline uint16_t f32_to_bf16(float f) {
    uint32_t u = __float_as_uint(f);
    uint32_t r = u + 0x7fffu + ((u >> 16) & 1u);
    return (uint16_t)(r >> 16);
}

// ---------------- threefry2x32 (JAX-exact core) ----------------
__host__ __device__ inline uint32_t rotl32_(uint32_t x, uint32_t r) {
    return (x << r) | (x >> (32u - r));
}

__host__ __device__ inline void tf2x32(uint32_t k0, uint32_t k1,
                                       uint32_t x0, uint32_t x1,
                                       uint32_t &o0, uint32_t &o1) {
    uint32_t ks2 = k0 ^ k1 ^ 0x1BD11BDAu;
    x0 += k0; x1 += k1;
#define TF_R4(a,b,c,d) \
    x0 += x1; x1 = rotl32_(x1,(a)); x1 ^= x0; \
    x0 += x1; x1 = rotl32_(x1,(b)); x1 ^= x0; \
    x0 += x1; x1 = rotl32_(x1,(c)); x1 ^= x0; \
    x0 += x1; x1 = rotl32_(x1,(d)); x1 ^= x0;
    TF_R4(13,15,26,6)  x0 += k1;  x1 += ks2 + 1u;
    TF_R4(17,29,16,24) x0 += ks2; x1 += k0 + 2u;
    TF_R4(13,15,26,6)  x0 += k0;  x1 += k1 + 3u;
    TF_R4(17,29,16,24) x0 += k1;  x1 += ks2 + 4u;
    TF_R4(13,15,26,6)  x0 += ks2; x1 += k0 + 5u;
#undef TF_R4
    o0 = x0; o1 = x1;
}

// 0.2*bernoulli, JAX partitionable-threefry (verified R4): counter (0, idx),
// bits = o0 ^ o1, f32 uniform, u < 0.004f.
__device__ inline float noise_add(uint32_t k0, uint32_t k1, uint32_t idx) {
    uint32_t o0, o1;
    tf2x32(k0, k1, 0u, idx, o0, o1);
    uint32_t bits = o0 ^ o1;
    float u = __uint_as_float((bits >> 9) | 0x3f800000u) - 1.0f;
    return (u < 0.004f) ? 0.2f : 0.0f;
}

__device__ inline float sigmoidf_(float x) {
    return 1.0f / (1.0f + expf(-x));
}

// ---------------- init: ec3 = 0 (f32 + bf16), ec5 = ec5_init ----------------
__global__ void init_kernel(const float* __restrict__ ec5_init,
                            float* __restrict__ ec3, float* __restrict__ ec5,
                            uint16_t* __restrict__ ec3bf, int n) {
    int i = blockIdx.x * blockDim.x + threadIdx.x;
    if (i < n) { ec3[i] = 0.0f; ec5[i] = ec5_init[i]; ec3bf[i] = 0; }
}

// ---------------- drive[t][c] (f64 internal, f32 out; runs once) ----------------
__global__ void drive_kernel(const float* __restrict__ wca3ca1, float* __restrict__ drive) {
    int t = blockIdx.x;
    int c0 = threadIdx.x;
    const float stepf = 100.0f / 1023.0f;
    double x = (double)t;
    double acc[4] = {0.0, 0.0, 0.0, 0.0};
    for (int j = 0; j < 1024; ++j) {
        float cj = stepf * (float)j;
        double d = (double)cj - x;
        double g = exp(-(d * d) / 50.0);
        #pragma unroll
        for (int i = 0; i < 4; ++i)
            acc[i] += g * (double)wca3ca1[(size_t)j * CA1N + c0 + i * 256];
    }
    #pragma unroll
    for (int i = 0; i < 4; ++i)
        drive[(size_t)t * CA1N + c0 + i * 256] = (float)acc[i];
}

// ---------------- Wt_bf16[n][k] = bf16(W[k][n]), 1024x1024, runs once ----------------
__global__ __launch_bounds__(256) void wtrans_kernel(const float* __restrict__ W,
                                                     uint16_t* __restrict__ Wt) {
    __shared__ float tile[32][33];
    int k0 = blockIdx.x * 32, n0 = blockIdx.y * 32;
    int tx = threadIdx.x & 31, ty = threadIdx.x >> 5;   // 32x8
    #pragma unroll
    for (int i = 0; i < 32; i += 8)
        tile[ty + i][tx] = W[(size_t)(k0 + ty + i) * 1024 + n0 + tx];
    __syncthreads();
    #pragma unroll
    for (int i = 0; i < 32; i += 8)
        Wt[(size_t)(n0 + ty + i) * 1024 + k0 + tx] = f32_to_bf16(tile[tx][ty + i]);
}

// ---------------- 128x128 bf16 MFMA tile core ----------------
// A: [rows][K] bf16 row-major, B: [cols][K] bf16 row-major (i.e. W^T).
// LDS tiles [128][BK] with slot-XOR swizzle (slot p holds global slot p^(row&3)).
__device__ inline void mfma_tile(const uint16_t* __restrict__ Abf,
                                 const uint16_t* __restrict__ Bbf,
                                 int row0, int col0, int K,
                                 short* As, short* Bs, f32x4 acc[4][4]) {
    const int tid = threadIdx.x;
    const int wid = tid >> 6, lane = tid & 63;
    const int wr = wid >> 1, wc = wid & 1;
    const int l15 = lane & 15, l4 = lane >> 4;
    // staging: chunk idx = it*256+tid -> (row=idx>>2, physical slot p=idx&3);
    // source slot = p ^ (row&3)
    const int ra0 = tid >> 2;
    const int ra1 = (tid + 256) >> 2;
    const int sa0 = ((tid & 3) ^ (ra0 & 3)) << 3;   // element offset of source slot
    const int sa1 = ((tid & 3) ^ (ra1 & 3)) << 3;
    const size_t aoff0 = (size_t)(row0 + ra0) * K + sa0;
    const size_t aoff1 = (size_t)(row0 + ra1) * K + sa1;
    const size_t boff0 = (size_t)(col0 + ra0) * K + sa0;
    const size_t boff1 = (size_t)(col0 + ra1) * K + sa1;
    // frag read offsets (shorts): row*BK + (l4^(row&3))*8
    int arow = wr * 64 + l15, brow = wc * 64 + l15;
    const int swz = l4 ^ (l15 & 3);

    uint4 av0 = *(const uint4*)&Abf[aoff0];
    uint4 av1 = *(const uint4*)&Abf[aoff1];
    uint4 bv0 = *(const uint4*)&Bbf[boff0];
    uint4 bv1 = *(const uint4*)&Bbf[boff1];

    for (int k0 = 0; k0 < K; k0 += BK) {
        __syncthreads();
        *(uint4*)&As[tid * 8] = av0;
        *(uint4*)&As[(tid + 256) * 8] = av1;
        *(uint4*)&Bs[tid * 8] = bv0;
        *(uint4*)&Bs[(tid + 256) * 8] = bv1;
        __syncthreads();
        if (k0 + BK < K) {   // prefetch next chunk during compute
            av0 = *(const uint4*)&Abf[aoff0 + k0 + BK];
            av1 = *(const uint4*)&Abf[aoff1 + k0 + BK];
            bv0 = *(const uint4*)&Bbf[boff0 + k0 + BK];
            bv1 = *(const uint4*)&Bbf[boff1 + k0 + BK];
        }
        bf16x8 a[4], b[4];
        #pragma unroll
        for (int m = 0; m < 4; ++m) {
            a[m] = *(const bf16x8*)&As[(arow + m * 16) * BK + swz * 8];
            b[m] = *(const bf16x8*)&Bs[(brow + m * 16) * BK + swz * 8];
        }
        #pragma unroll
        for (int m = 0; m < 4; ++m)
            #pragma unroll
            for (int n = 0; n < 4; ++n)
                acc[m][n] = __builtin_amdgcn_mfma_f32_16x16x32_bf16(a[m], b[n], acc[m][n], 0, 0, 0);
    }
}

// gemm1: ca1 = relu(drv[c]*(1+sigmoid(ec3@W1)) - bias[c]); write bf16 (+f32 at t=99)
__global__ __launch_bounds__(256) void gemm1_kernel(
    const uint16_t* __restrict__ ec3bf, const uint16_t* __restrict__ W1t,
    const float* __restrict__ drv, const float* __restrict__ bias,
    uint16_t* __restrict__ ca1bf, float* __restrict__ ca1f, int writef32)
{
    __shared__ short As[128 * BK];
    __shared__ short Bs[128 * BK];
    f32x4 acc[4][4];
    #pragma unroll
    for (int m = 0; m < 4; ++m)
        #pragma unroll
        for (int n = 0; n < 4; ++n) {
            f32x4 z = {0.f, 0.f, 0.f, 0.f};
            acc[m][n] = z;
        }
    mfma_tile(ec3bf, W1t, blockIdx.x * 128, blockIdx.y * 128, ECN, As, Bs, acc);

    const int tid = threadIdx.x, wid = tid >> 6, lane = tid & 63;
    const int wr = wid >> 1, wc = wid & 1, l15 = lane & 15, l4 = lane >> 4;
    const int rbase = blockIdx.x * 128 + wr * 64 + l4 * 4;
    const int cbase = blockIdx.y * 128 + wc * 64 + l15;
    #pragma unroll
    for (int m = 0; m < 4; ++m) {
        #pragma unroll
        for (int n = 0; n < 4; ++n) {
            int c = cbase + n * 16;
            float dv = drv[c], bi = bias[c];
            #pragma unroll
            for (int e = 0; e < 4; ++e) {
                int r = rbase + m * 16 + e;
                float s = sigmoidf_(acc[m][n][e]);
                float v = dv * (1.0f + s) - bi;
                v = v > 0.0f ? v : 0.0f;
                size_t off = (size_t)r * CA1N + c;
                ca1bf[off] = f32_to_bf16(v);
                if (writef32) ca1f[off] = v;
            }
        }
    }
}

// gemm2: u = ec5 + ca1@W2 + bias; ec5' = 0.5+0.5*sig(4(u-0.5));
//        ec3' = ec5'*ec3 (+cue if inject) + noise. States f32; ec3 also bf16.
__global__ __launch_bounds__(256) void gemm2_kernel(
    const uint16_t* __restrict__ ca1bf, const uint16_t* __restrict__ W2t,
    const float* __restrict__ cue, const float* __restrict__ bias,
    float* __restrict__ ec3, float* __restrict__ ec5, uint16_t* __restrict__ ec3bf,
    uint32_t k0_, uint32_t k1_, int inject)
{
    __shared__ short As[128 * BK];
    __shared__ short Bs[128 * BK];
    f32x4 acc[4][4];
    #pragma unroll
    for (int m = 0; m < 4; ++m)
        #pragma unroll
        for (int n = 0; n < 4; ++n) {
            f32x4 z = {0.f, 0.f, 0.f, 0.f};
            acc[m][n] = z;
        }
    mfma_tile(ca1bf, W2t, blockIdx.x * 128, blockIdx.y * 128, CA1N, As, Bs, acc);

    const int tid = threadIdx.x, wid = tid >> 6, lane = tid & 63;
    const int wr = wid >> 1, wc = wid & 1, l15 = lane & 15, l4 = lane >> 4;
    const int rbase = blockIdx.x * 128 + wr * 64 + l4 * 4;
    const int cbase = blockIdx.y * 128 + wc * 64 + l15;
    #pragma unroll
    for (int m = 0; m < 4; ++m) {
        #pragma unroll
        for (int n = 0; n < 4; ++n) {
            int c = cbase + n * 16;
            float bi = bias[c];
            #pragma unroll
            for (int e = 0; e < 4; ++e) {
                int r = rbase + m * 16 + e;
                size_t off = (size_t)r * ECN + c;
                float u = ec5[off] + acc[m][n][e] + bi;
                float e5n = 0.5f + 0.5f * sigmoidf_(4.0f * (u - 0.5f));
                float e3n = e5n * ec3[off];
                if (inject) e3n += cue[off];
                e3n += noise_add(k0_, k1_, (uint32_t)off);
                ec5[off] = e5n;
                ec3[off] = e3n;
                ec3bf[off] = f32_to_bf16(e3n);
            }
        }
    }
}

// out[b][:2] = ca1[b] @ wca1act + actbias (f64 accumulate, one wave per row)
__global__ __launch_bounds__(256) void final_kernel(
    const float* __restrict__ ca1,
    const float* __restrict__ wact,
    const float* __restrict__ actbias,
    float* __restrict__ out)
{
    int wave = threadIdx.x >> 6, lane = threadIdx.x & 63;
    int b = blockIdx.x * 4 + wave;
    double a0 = 0.0, a1 = 0.0;
    for (int c = lane; c < CA1N; c += 64) {
        double v = (double)ca1[(size_t)b * CA1N + c];
        a0 += v * (double)wact[c * 2 + 0];
        a1 += v * (double)wact[c * 2 + 1];
    }
    #pragma unroll
    for (int off = 32; off > 0; off >>= 1) {
        a0 += __shfl_down(a0, off);
        a1 += __shfl_down(a1, off);
    }
    if (lane == 0) {
        out[(size_t)b * 2 + 0] = (float)(a0 + (double)actbias[0]);
        out[(size_t)b * 2 + 1] = (float)(a1 + (double)actbias[1]);
    }
}

// ---------------- host ----------------
extern "C" void kernel_launch(void* const* d_in, const int* in_sizes, int n_in,
                              void* d_out, int out_size, void* d_ws, size_t ws_size,
                              hipStream_t stream) {
    const float* cue      = (const float*)d_in[0];
    const float* ec5_init = (const float*)d_in[1];
    const float* wca3ca1  = (const float*)d_in[2];
    const float* wec3ca1  = (const float*)d_in[3];
    const float* wca1ec5  = (const float*)d_in[4];
    const float* wca1act  = (const float*)d_in[5];
    const float* ca1bias  = (const float*)d_in[6];
    const float* ec5bias  = (const float*)d_in[7];
    const float* actbias  = (const float*)d_in[8];
    float* out = (float*)d_out;

    const size_t NE = (size_t)BS * ECN;
    char* p = (char*)d_ws;
    float*    ec3   = (float*)p;            p += NE * 4;            // 32 MB
    float*    ec5   = (float*)p;            p += NE * 4;            // 32 MB
    float*    ca1f  = (float*)p;            p += NE * 4;            // 32 MB
    uint16_t* ec3bf = (uint16_t*)p;         p += NE * 2;            // 16 MB
    uint16_t* ca1bf = (uint16_t*)p;         p += NE * 2;            // 16 MB
    uint16_t* W1t   = (uint16_t*)p;         p += (size_t)ECN * CA1N * 2;  // 2 MB
    uint16_t* W2t   = (uint16_t*)p;         p += (size_t)CA1N * ECN * 2;  // 2 MB
    float*    drive = (float*)p;                                     // 0.4 MB

    const int n = (int)NE;
    hipLaunchKernelGGL(init_kernel, dim3((n + 255) / 256), dim3(256), 0, stream,
                       ec5_init, ec3, ec5, ec3bf, n);
    hipLaunchKernelGGL(drive_kernel, dim3(T_STEPS), dim3(256), 0, stream,
                       wca3ca1, drive);
    hipLaunchKernelGGL(wtrans_kernel, dim3(32, 32), dim3(256), 0, stream, wec3ca1, W1t);
    hipLaunchKernelGGL(wtrans_kernel, dim3(32, 32), dim3(256), 0, stream, wca1ec5, W2t);

    dim3 blk(256);
    dim3 gg(BS / 128, 1024 / 128);   // (64, 8)
    for (int t = 0; t < T_STEPS; ++t) {
        hipLaunchKernelGGL(gemm1_kernel, gg, blk, 0, stream,
                           ec3bf, W1t, drive + (size_t)t * CA1N, ca1bias,
                           ca1bf, ca1f, (t == T_STEPS - 1) ? 1 : 0);
        if (t < T_STEPS - 1) {
            uint32_t k0, k1;
            tf2x32(0u, 42u, 0u, (uint32_t)t, k0, k1);   // fold_in(key(42), t)
            hipLaunchKernelGGL(gemm2_kernel, gg, blk, 0, stream,
                               ca1bf, W2t, cue, ec5bias, ec3, ec5, ec3bf, k0, k1,
                               (t == CUE_T) ? 1 : 0);
        }
    }
    hipLaunchKernelGGL(final_kernel, dim3(BS / 4), blk, 0, stream,
                       ca1f, wca1act, actbias, out);
}

// Round 6
// 8052.748 us; speedup vs baseline: 11.7019x; 1.1203x over previous
//
#include <hip/hip_runtime.h>
#include <stdint.h>

#define BS 8192
#define NDIM 1024
#define T_STEPS 100
#define CUE_T 10
#define BK 64

typedef __attribute__((ext_vector_type(8))) short bf16x8;
typedef __attribute__((ext_vector_type(16))) float f32x16;

// ---------------- bf16 helpers (RNE, XLA-compatible) ----------------
__device__ inline uint16_t f32_to_bf16(float f) {
    uint32_t u = __float_as_uint(f);
    uint32_t r = u + 0x7fffu + ((u >> 16) & 1u);
    return (uint16_t)(r >> 16);
}
__device__ inline float bf16_to_f32(uint16_t h) {
    return __uint_as_float(((uint32_t)h) << 16);
}

// ---------------- threefry2x32 (JAX-exact core) ----------------
__host__ __device__ inline uint32_t rotl32_(uint32_t x, uint32_t r) {
    return (x << r) | (x >> (32u - r));
}

__host__ __device__ inline void tf2x32(uint32_t k0, uint32_t k1,
                                       uint32_t x0, uint32_t x1,
                                       uint32_t &o0, uint32_t &o1) {
    uint32_t ks2 = k0 ^ k1 ^ 0x1BD11BDAu;
    x0 += k0; x1 += k1;
#define TF_R4(a,b,c,d) \
    x0 += x1; x1 = rotl32_(x1,(a)); x1 ^= x0; \
    x0 += x1; x1 = rotl32_(x1,(b)); x1 ^= x0; \
    x0 += x1; x1 = rotl32_(x1,(c)); x1 ^= x0; \
    x0 += x1; x1 = rotl32_(x1,(d)); x1 ^= x0;
    TF_R4(13,15,26,6)  x0 += k1;  x1 += ks2 + 1u;
    TF_R4(17,29,16,24) x0 += ks2; x1 += k0 + 2u;
    TF_R4(13,15,26,6)  x0 += k0;  x1 += k1 + 3u;
    TF_R4(17,29,16,24) x0 += k1;  x1 += ks2 + 4u;
    TF_R4(13,15,26,6)  x0 += ks2; x1 += k0 + 5u;
#undef TF_R4
    o0 = x0; o1 = x1;
}

// 0.2*bernoulli, JAX partitionable-threefry (verified R4/R5): counter (0, idx),
// bits = o0 ^ o1, f32 uniform, u < 0.004f.
__device__ inline float noise_add(uint32_t k0, uint32_t k1, uint32_t idx) {
    uint32_t o0, o1;
    tf2x32(k0, k1, 0u, idx, o0, o1);
    uint32_t bits = o0 ^ o1;
    float u = __uint_as_float((bits >> 9) | 0x3f800000u) - 1.0f;
    return (u < 0.004f) ? 0.2f : 0.0f;
}

__device__ inline float sigmoidf_(float x) {
    return 1.0f / (1.0f + expf(-x));
}

// ---------------- async global->LDS, 16B per lane ----------------
__device__ __forceinline__ void gload16(const uint16_t* g, uint16_t* l) {
    __builtin_amdgcn_global_load_lds(
        (const __attribute__((address_space(1))) void*)g,
        (__attribute__((address_space(3))) void*)l, 16, 0, 0);
}

// ---------------- init: ec3bf = 0, ec5bf = bf16(ec5_init) ----------------
__global__ void init_kernel(const float* __restrict__ ec5_init,
                            uint16_t* __restrict__ ec3bf,
                            uint16_t* __restrict__ ec5bf, int n) {
    int i = blockIdx.x * blockDim.x + threadIdx.x;
    if (i < n) { ec3bf[i] = 0; ec5bf[i] = f32_to_bf16(ec5_init[i]); }
}

// ---------------- drive[t][c] = sum_j exp(-(cen_j - t)^2/50) * W[j][c] ----------------
// grid (25, 4): 4 t-values x 256 cols per block; gaussians staged in LDS.
__global__ __launch_bounds__(256) void drive_kernel(const float* __restrict__ W,
                                                    float* __restrict__ drive) {
    __shared__ float g[4][1024];
    const int t0 = blockIdx.x * 4;
    const int c = blockIdx.y * 256 + threadIdx.x;
    const float stepf = 100.0f / 1023.0f;
    for (int i = threadIdx.x; i < 4096; i += 256) {
        int tt = i >> 10, j = i & 1023;
        float d = stepf * (float)j - (float)(t0 + tt);
        g[tt][j] = expf(-(d * d) * 0.02f);
    }
    __syncthreads();
    float a0 = 0.f, a1 = 0.f, a2 = 0.f, a3 = 0.f;
    for (int j = 0; j < 1024; ++j) {
        float w = W[(size_t)j * NDIM + c];
        a0 = fmaf(g[0][j], w, a0);
        a1 = fmaf(g[1][j], w, a1);
        a2 = fmaf(g[2][j], w, a2);
        a3 = fmaf(g[3][j], w, a3);
    }
    drive[(size_t)(t0 + 0) * NDIM + c] = a0;
    drive[(size_t)(t0 + 1) * NDIM + c] = a1;
    drive[(size_t)(t0 + 2) * NDIM + c] = a2;
    drive[(size_t)(t0 + 3) * NDIM + c] = a3;
}

// ---------------- Wt_bf16[n][k] = bf16(W[k][n]), runs once ----------------
__global__ __launch_bounds__(256) void wtrans_kernel(const float* __restrict__ W,
                                                     uint16_t* __restrict__ Wt) {
    __shared__ float tile[32][33];
    int k0 = blockIdx.x * 32, n0 = blockIdx.y * 32;
    int tx = threadIdx.x & 31, ty = threadIdx.x >> 5;
    #pragma unroll
    for (int i = 0; i < 32; i += 8)
        tile[ty + i][tx] = W[(size_t)(k0 + ty + i) * NDIM + n0 + tx];
    __syncthreads();
    #pragma unroll
    for (int i = 0; i < 32; i += 8)
        Wt[(size_t)(n0 + ty + i) * NDIM + k0 + tx] = f32_to_bf16(tile[tx][ty + i]);
}

// ---------------- 128x128 bf16 MFMA core (32x32x16, dbuf 2-phase) ----------------
// A: [8192][1024] bf16 row-major; Bt: [1024][1024] bf16 (W^T: [n][k]).
// LDS tiles [128][BK=64], slot-XOR swizzle (phys slot p holds logical p^(row&7)).
// 4 waves (2x2), 64x64/wave = 2x2 frags of 32x32; staged via global_load_lds w16.
__device__ __forceinline__ void gemm_core(const uint16_t* __restrict__ A,
                                          const uint16_t* __restrict__ Bt,
                                          uint16_t* As, uint16_t* Bs,
                                          f32x16 acc[2][2]) {
    const int tid = threadIdx.x;
    const int wid = tid >> 6, lane = tid & 63;
    const int row0 = blockIdx.x * 128, col0 = blockIdx.y * 128;
    // staging geometry: wave stages 4 A-chunks + 4 B-chunks of 1KB (8 rows x 128B)
    const int srow = lane >> 3;                 // row within chunk
    const int soff = ((lane & 7) ^ srow) * 8;   // pre-swizzled source k-offset
    const uint16_t* aS[4]; const uint16_t* bS[4];
    #pragma unroll
    for (int i = 0; i < 4; ++i) {
        int ch = wid * 4 + i;
        aS[i] = A  + (size_t)(row0 + ch * 8 + srow) * NDIM + soff;
        bS[i] = Bt + (size_t)(col0 + ch * 8 + srow) * NDIM + soff;
    }
    // fragment LDS element offsets: row*64 + physslot*8, physslot = slot^(row&7)
    const int l31 = lane & 31, l5 = lane >> 5;
    const int wr = wid >> 1, wc = wid & 1;
    int aoff[2][4], boff[2][4];
    #pragma unroll
    for (int m = 0; m < 2; ++m)
        #pragma unroll
        for (int kk = 0; kk < 4; ++kk) {
            int ar = wr * 64 + m * 32 + l31;
            aoff[m][kk] = ar * BK + ((((kk << 1) | l5) ^ (ar & 7)) << 3);
            int br = wc * 64 + m * 32 + l31;
            boff[m][kk] = br * BK + ((((kk << 1) | l5) ^ (br & 7)) << 3);
        }

    // prologue: stage K-tile 0 into buffer 0
    #pragma unroll
    for (int i = 0; i < 4; ++i) {
        int ch = wid * 4 + i;
        gload16(aS[i], As + ch * 512);
        gload16(bS[i], Bs + ch * 512);
    }
    __syncthreads();

    int cur = 0;
    for (int kt = 0; kt < NDIM / BK; ++kt) {
        if (kt + 1 < NDIM / BK) {               // stage next tile into other buffer
            const int nb = (cur ^ 1) * 8192;
            const int k0n = (kt + 1) * BK;
            #pragma unroll
            for (int i = 0; i < 4; ++i) {
                int ch = wid * 4 + i;
                gload16(aS[i] + k0n, As + nb + ch * 512);
                gload16(bS[i] + k0n, Bs + nb + ch * 512);
            }
        }
        const uint16_t* as = As + cur * 8192;
        const uint16_t* bs = Bs + cur * 8192;
        bf16x8 af[2][4], bfr[2][4];
        #pragma unroll
        for (int m = 0; m < 2; ++m)
            #pragma unroll
            for (int kk = 0; kk < 4; ++kk) {
                af[m][kk]  = *(const bf16x8*)&as[aoff[m][kk]];
                bfr[m][kk] = *(const bf16x8*)&bs[boff[m][kk]];
            }
        #pragma unroll
        for (int kk = 0; kk < 4; ++kk)
            #pragma unroll
            for (int m = 0; m < 2; ++m)
                #pragma unroll
                for (int n = 0; n < 2; ++n)
                    acc[m][n] = __builtin_amdgcn_mfma_f32_32x32x16_bf16(
                        af[m][kk], bfr[n][kk], acc[m][n], 0, 0, 0);
        __syncthreads();   // drains vmcnt (next tile landed) + protects cur buffer
        cur ^= 1;
    }
}

// C/D layout of 32x32 MFMA: col = lane&31, row = (reg&3) + 8*(reg>>2) + 4*(lane>>5)
#define EPILOGUE_INDEX() \
    const int tid = threadIdx.x, wid = tid >> 6, lane = tid & 63; \
    const int wr = wid >> 1, wc = wid & 1, l31 = lane & 31, l5 = lane >> 5; \
    const int row0 = blockIdx.x * 128, col0 = blockIdx.y * 128;

// gemm1: ca1 = relu(drv[c]*(1+sigmoid(ec3@W1)) - bias[c]) -> bf16 (+f32 at t=99)
__global__ __launch_bounds__(256) void gemm1_kernel(
    const uint16_t* __restrict__ ec3bf, const uint16_t* __restrict__ W1t,
    const float* __restrict__ drv, const float* __restrict__ bias,
    uint16_t* __restrict__ ca1bf, float* __restrict__ ca1f, int writef32)
{
    __shared__ uint16_t As[2 * 128 * BK];
    __shared__ uint16_t Bs[2 * 128 * BK];
    f32x16 acc[2][2];
    #pragma unroll
    for (int m = 0; m < 2; ++m)
        #pragma unroll
        for (int n = 0; n < 2; ++n)
            acc[m][n] = (f32x16)(0.0f);
    gemm_core(ec3bf, W1t, As, Bs, acc);

    EPILOGUE_INDEX();
    #pragma unroll
    for (int m = 0; m < 2; ++m)
        #pragma unroll
        for (int n = 0; n < 2; ++n) {
            int c = col0 + wc * 64 + n * 32 + l31;
            float dv = drv[c], bi = bias[c];
            #pragma unroll
            for (int e = 0; e < 16; ++e) {
                int r = row0 + wr * 64 + m * 32 + (e & 3) + ((e >> 2) << 3) + (l5 << 2);
                float s = sigmoidf_(acc[m][n][e]);
                float v = dv * (1.0f + s) - bi;
                v = v > 0.0f ? v : 0.0f;
                size_t off = (size_t)r * NDIM + c;
                ca1bf[off] = f32_to_bf16(v);
                if (writef32) ca1f[off] = v;
            }
        }
}

// gemm2: u = ec5 + ca1@W2 + bias; ec5' = 0.5+0.5*sig(4(u-0.5));
//        ec3' = ec5'*ec3 (+cue if inject) + noise. All state bf16.
__global__ __launch_bounds__(256) void gemm2_kernel(
    const uint16_t* __restrict__ ca1bf, const uint16_t* __restrict__ W2t,
    const float* __restrict__ cue, const float* __restrict__ bias,
    uint16_t* __restrict__ ec3bf, uint16_t* __restrict__ ec5bf,
    uint32_t k0_, uint32_t k1_, int inject)
{
    __shared__ uint16_t As[2 * 128 * BK];
    __shared__ uint16_t Bs[2 * 128 * BK];
    f32x16 acc[2][2];
    #pragma unroll
    for (int m = 0; m < 2; ++m)
        #pragma unroll
        for (int n = 0; n < 2; ++n)
            acc[m][n] = (f32x16)(0.0f);
    gemm_core(ca1bf, W2t, As, Bs, acc);

    EPILOGUE_INDEX();
    #pragma unroll
    for (int m = 0; m < 2; ++m)
        #pragma unroll
        for (int n = 0; n < 2; ++n) {
            int c = col0 + wc * 64 + n * 32 + l31;
            float bi = bias[c];
            #pragma unroll
            for (int e = 0; e < 16; ++e) {
                int r = row0 + wr * 64 + m * 32 + (e & 3) + ((e >> 2) << 3) + (l5 << 2);
                size_t off = (size_t)r * NDIM + c;
                float e5 = bf16_to_f32(ec5bf[off]);
                float e3 = bf16_to_f32(ec3bf[off]);
                float u = e5 + acc[m][n][e] + bi;
                float e5n = 0.5f + 0.5f * sigmoidf_(4.0f * (u - 0.5f));
                float e3n = e5n * e3;
                if (inject) e3n += cue[off];
                e3n += noise_add(k0_, k1_, (uint32_t)off);
                ec5bf[off] = f32_to_bf16(e5n);
                ec3bf[off] = f32_to_bf16(e3n);
            }
        }
}

// out[b][:2] = ca1[b] @ wca1act + actbias (f64 accumulate, one wave per row)
__global__ __launch_bounds__(256) void final_kernel(
    const float* __restrict__ ca1,
    const float* __restrict__ wact,
    const float* __restrict__ actbias,
    float* __restrict__ out)
{
    int wave = threadIdx.x >> 6, lane = threadIdx.x & 63;
    int b = blockIdx.x * 4 + wave;
    double a0 = 0.0, a1 = 0.0;
    for (int c = lane; c < NDIM; c += 64) {
        double v = (double)ca1[(size_t)b * NDIM + c];
        a0 += v * (double)wact[c * 2 + 0];
        a1 += v * (double)wact[c * 2 + 1];
    }
    #pragma unroll
    for (int off = 32; off > 0; off >>= 1) {
        a0 += __shfl_down(a0, off);
        a1 += __shfl_down(a1, off);
    }
    if (lane == 0) {
        out[(size_t)b * 2 + 0] = (float)(a0 + (double)actbias[0]);
        out[(size_t)b * 2 + 1] = (float)(a1 + (double)actbias[1]);
    }
}

// ---------------- host ----------------
extern "C" void kernel_launch(void* const* d_in, const int* in_sizes, int n_in,
                              void* d_out, int out_size, void* d_ws, size_t ws_size,
                              hipStream_t stream) {
    const float* cue      = (const float*)d_in[0];
    const float* ec5_init = (const float*)d_in[1];
    const float* wca3ca1  = (const float*)d_in[2];
    const float* wec3ca1  = (const float*)d_in[3];
    const float* wca1ec5  = (const float*)d_in[4];
    const float* wca1act  = (const float*)d_in[5];
    const float* ca1bias  = (const float*)d_in[6];
    const float* ec5bias  = (const float*)d_in[7];
    const float* actbias  = (const float*)d_in[8];
    float* out = (float*)d_out;

    const size_t NE = (size_t)BS * NDIM;
    char* p = (char*)d_ws;
    float*    ca1f  = (float*)p;      p += NE * 4;                 // 32 MB
    uint16_t* ec3bf = (uint16_t*)p;   p += NE * 2;                 // 16 MB
    uint16_t* ec5bf = (uint16_t*)p;   p += NE * 2;                 // 16 MB
    uint16_t* ca1bf = (uint16_t*)p;   p += NE * 2;                 // 16 MB
    uint16_t* W1t   = (uint16_t*)p;   p += (size_t)NDIM * NDIM * 2; // 2 MB
    uint16_t* W2t   = (uint16_t*)p;   p += (size_t)NDIM * NDIM * 2; // 2 MB
    float*    drive = (float*)p;                                    // 0.4 MB

    const int n = (int)NE;
    hipLaunchKernelGGL(init_kernel, dim3((n + 255) / 256), dim3(256), 0, stream,
                       ec5_init, ec3bf, ec5bf, n);
    hipLaunchKernelGGL(drive_kernel, dim3(25, 4), dim3(256), 0, stream,
                       wca3ca1, drive);
    hipLaunchKernelGGL(wtrans_kernel, dim3(32, 32), dim3(256), 0, stream, wec3ca1, W1t);
    hipLaunchKernelGGL(wtrans_kernel, dim3(32, 32), dim3(256), 0, stream, wca1ec5, W2t);

    dim3 blk(256);
    dim3 gg(BS / 128, NDIM / 128);   // (64, 8) = 512 blocks
    for (int t = 0; t < T_STEPS; ++t) {
        hipLaunchKernelGGL(gemm1_kernel, gg, blk, 0, stream,
                           ec3bf, W1t, drive + (size_t)t * NDIM, ca1bias,
                           ca1bf, ca1f, (t == T_STEPS - 1) ? 1 : 0);
        if (t < T_STEPS - 1) {
            uint32_t k0, k1;
            tf2x32(0u, 42u, 0u, (uint32_t)t, k0, k1);   // fold_in(key(42), t)
            hipLaunchKernelGGL(gemm2_kernel, gg, blk, 0, stream,
                               ca1bf, W2t, cue, ec5bias, ec3bf, ec5bf, k0, k1,
                               (t == CUE_T) ? 1 : 0);
        }
    }
    hipLaunchKernelGGL(final_kernel, dim3(BS / 4), blk, 0, stream,
                       ca1f, wca1act, actbias, out);
}